// Round 1
// baseline (346.868 us; speedup 1.0000x reference)
//
#include <hip/hip_runtime.h>
#include <stdint.h>

typedef __bf16 bf16_t;
typedef __bf16 bf16x8 __attribute__((ext_vector_type(8)));
typedef __bf16 bf16x4 __attribute__((ext_vector_type(4)));
typedef float  f32x4  __attribute__((ext_vector_type(4)));

#define DEV __device__ __forceinline__

// async global->LDS, 16B per lane. LDS dest is wave-uniform base + lane*16.
DEV void gload16(const void* g, void* l) {
  __builtin_amdgcn_global_load_lds(
      (const __attribute__((address_space(1))) void*)g,
      (__attribute__((address_space(3))) void*)(uint32_t)(uintptr_t)l,
      16, 0, 0);
}

// ---------------------------------------------------------------------------
// NT GEMM: C[m][n] = sum_k A[m][k] * B[n][k]  (+ bias), A/B bf16, acc fp32.
// lda = ldb = K, ldc = N. Tile 128x128, BK=64, 256 threads (4 waves, 2x2).
// BIAS: 0 none, 1 bias[n], 2 bias[m]. CMODE: 0 none, 1 causal block skip
// (scores), 2 causal k-limit (PV).
// ---------------------------------------------------------------------------
template<bool OUT_BF16, int BIAS, int CMODE>
__global__ __launch_bounds__(256, 2) void gemm_nt(
    const bf16_t* __restrict__ A, const bf16_t* __restrict__ B,
    void* __restrict__ Cv, const float* __restrict__ bias,
    int M, int N, int K, long sA, long sB, long sC)
{
  const int tm = blockIdx.x, tn = blockIdx.y, bz = blockIdx.z;
  if (CMODE == 1 && tn > tm) return;          // fully-masked score tile
  const int m0 = tm * 128, n0 = tn * 128;
  int kmax = K;
  if (CMODE == 2) { int t = m0 + 128; kmax = t < K ? t : K; }
  A += (long)bz * sA;
  B += (long)bz * sB;

  __shared__ __align__(16) bf16_t ldsA[128 * 64];
  __shared__ __align__(16) bf16_t ldsB[128 * 64];

  const int tid  = threadIdx.x;
  const int lane = tid & 63;
  const int wave = tid >> 6;
  const int wm = wave & 1, wn = wave >> 1;    // wave quadrant (2x2 of 64x64)
  const int l8r = lane >> 3;                  // row within 8-row staging block
  const int l8c = (lane & 7) * 8;             // k-offset (elements) for staging
  const int cl  = lane & 15;                  // fragment m/n index
  const int qd  = lane >> 4;                  // quad -> k-slice of fragment

  f32x4 acc[4][4] = {};

  for (int k0 = 0; k0 < kmax; k0 += 64) {
    #pragma unroll
    for (int t = 0; t < 4; ++t) {
      const int rb = wave * 4 + t;            // 8-row block index (wave-uniform)
      gload16(A + (long)(m0 + rb * 8 + l8r) * K + (k0 + l8c), &ldsA[rb * 8 * 64]);
      gload16(B + (long)(n0 + rb * 8 + l8r) * K + (k0 + l8c), &ldsB[rb * 8 * 64]);
    }
    __syncthreads();
    #pragma unroll
    for (int kk = 0; kk < 64; kk += 32) {
      bf16x8 af[4], bg[4];
      #pragma unroll
      for (int i = 0; i < 4; ++i)
        af[i] = *(const bf16x8*)&ldsA[(wm * 64 + i * 16 + cl) * 64 + kk + qd * 8];
      #pragma unroll
      for (int j = 0; j < 4; ++j)
        bg[j] = *(const bf16x8*)&ldsB[(wn * 64 + j * 16 + cl) * 64 + kk + qd * 8];
      #pragma unroll
      for (int i = 0; i < 4; ++i)
        #pragma unroll
        for (int j = 0; j < 4; ++j)
          acc[i][j] = __builtin_amdgcn_mfma_f32_16x16x32_bf16(af[i], bg[j], acc[i][j], 0, 0, 0);
    }
    __syncthreads();
  }

  // Epilogue. C/D layout: col = lane&15, row = (lane>>4)*4 + reg.
  const long cbase = (long)bz * sC;
  #pragma unroll
  for (int i = 0; i < 4; ++i) {
    #pragma unroll
    for (int j = 0; j < 4; ++j) {
      const int gn  = n0 + wn * 64 + j * 16 + cl;
      const int gm0 = m0 + wm * 64 + i * 16 + qd * 4;
      float bn = (BIAS == 1) ? bias[gn] : 0.0f;
      #pragma unroll
      for (int r = 0; r < 4; ++r) {
        const int gm = gm0 + r;
        float v = acc[i][j][r] + bn;
        if (BIAS == 2) v += bias[gm];
        if (OUT_BF16) ((bf16_t*)Cv)[cbase + (long)gm * N + gn] = (bf16_t)v;
        else          ((float*) Cv)[cbase + (long)gm * N + gn] = v;
      }
    }
  }
}

// ---------------------------------------------------------------------------
// Row-wise causal softmax: scores fp32 [4][2048][2048] -> probs bf16, with
// scale 1/32 and zero-fill up to the row's 128-aligned k-tile boundary.
// One 256-thread block per row.
// ---------------------------------------------------------------------------
__global__ __launch_bounds__(256) void softmax_causal(
    const float* __restrict__ S, bf16_t* __restrict__ P)
{
  const int row = blockIdx.x;
  const int b = row >> 11, r = row & 2047;
  const float* s = S + ((long)b * 2048 + r) * 2048;
  bf16_t*      p = P + ((long)b * 2048 + r) * 2048;
  const int L = r + 1;
  const float scale = 0.03125f;
  __shared__ float red[8];

  float m = -3.0e38f;
  for (int j = threadIdx.x; j < L; j += 256) m = fmaxf(m, s[j]);
  #pragma unroll
  for (int o = 32; o > 0; o >>= 1) m = fmaxf(m, __shfl_xor(m, o, 64));
  if ((threadIdx.x & 63) == 0) red[threadIdx.x >> 6] = m;
  __syncthreads();
  m = fmaxf(fmaxf(red[0], red[1]), fmaxf(red[2], red[3]));
  __syncthreads();

  float sum = 0.f;
  for (int j = threadIdx.x; j < L; j += 256) sum += __expf((s[j] - m) * scale);
  #pragma unroll
  for (int o = 32; o > 0; o >>= 1) sum += __shfl_xor(sum, o, 64);
  if ((threadIdx.x & 63) == 0) red[4 + (threadIdx.x >> 6)] = sum;
  __syncthreads();
  sum = red[4] + red[5] + red[6] + red[7];
  const float inv = 1.0f / sum;

  for (int j = threadIdx.x; j < L; j += 256)
    p[j] = (bf16_t)(__expf((s[j] - m) * scale) * inv);
  const int Lz = (r & ~127) + 128;            // PV kernel reads k < this
  for (int j = L + threadIdx.x; j < Lz; j += 256) p[j] = (bf16_t)0.0f;
}

// fp32 -> bf16 elementwise (x), 4 elems/thread
__global__ __launch_bounds__(256) void cvt_x(
    const float4* __restrict__ in, bf16x4* __restrict__ out, int n4)
{
  const int i = blockIdx.x * 256 + threadIdx.x;
  if (i >= n4) return;
  float4 f = in[i];
  bf16x4 o;
  o.x = (__bf16)f.x; o.y = (__bf16)f.y; o.z = (__bf16)f.z; o.w = (__bf16)f.w;
  out[i] = o;
}

// W[k][n] fp32 (1024x1024) -> WT[n][k] bf16, 32x32 LDS tile transpose
__global__ __launch_bounds__(256) void cvt_w_t(
    const float* __restrict__ W, bf16_t* __restrict__ WT)
{
  __shared__ float t[32][33];
  const int bx = blockIdx.x, by = blockIdx.y;
  const int tx = threadIdx.x & 31, ty = threadIdx.x >> 5;  // 32 x 8
  #pragma unroll
  for (int dy = 0; dy < 32; dy += 8)
    t[ty + dy][tx] = W[(long)(by * 32 + ty + dy) * 1024 + bx * 32 + tx];
  __syncthreads();
  #pragma unroll
  for (int dy = 0; dy < 32; dy += 8)
    WT[(long)(bx * 32 + ty + dy) * 1024 + by * 32 + tx] = (bf16_t)t[tx][ty + dy];
}

// ---------------------------------------------------------------------------
extern "C" void kernel_launch(void* const* d_in, const int* in_sizes, int n_in,
                              void* d_out, int out_size, void* d_ws, size_t ws_size,
                              hipStream_t stream) {
  const float* x  = (const float*)d_in[0];
  const float* Wq = (const float*)d_in[1];
  const float* bq = (const float*)d_in[2];
  const float* Wk = (const float*)d_in[3];
  const float* bk = (const float*)d_in[4];
  const float* Wv = (const float*)d_in[5];
  const float* bv = (const float*)d_in[6];
  const float* Wo = (const float*)d_in[7];
  const float* bo = (const float*)d_in[8];
  float* out = (float*)d_out;

  const int Bb = 4, S = 2048, D = 1024;
  const int MF = Bb * S;                       // 8192 flattened tokens
  size_t off = 0;
  auto alloc = [&](size_t bytes) -> void* {
    void* p = (char*)d_ws + off;
    off += (bytes + 255) & ~(size_t)255;
    return p;
  };
  bf16_t* x_b   = (bf16_t*)alloc((size_t)MF * D * 2);       // 16.8 MB
  bf16_t* WqT   = (bf16_t*)alloc((size_t)D * D * 2);
  bf16_t* WkT   = (bf16_t*)alloc((size_t)D * D * 2);
  bf16_t* WvT   = (bf16_t*)alloc((size_t)D * D * 2);
  bf16_t* WoT   = (bf16_t*)alloc((size_t)D * D * 2);
  bf16_t* q_b   = (bf16_t*)alloc((size_t)MF * D * 2);
  bf16_t* k_b   = (bf16_t*)alloc((size_t)MF * D * 2);
  bf16_t* vT_b  = (bf16_t*)alloc((size_t)Bb * D * S * 2);   // per-batch [D][S]
  float*  sc    = (float*) alloc((size_t)Bb * S * S * 4);   // 67 MB
  bf16_t* probs = (bf16_t*)alloc((size_t)Bb * S * S * 2);   // 33.5 MB
  bf16_t* attn  = (bf16_t*)alloc((size_t)MF * D * 2);

  // 1. convert inputs to bf16 (weights transposed so all GEMMs are NT)
  cvt_x<<<dim3((MF * D / 4 + 255) / 256), 256, 0, stream>>>(
      (const float4*)x, (bf16x4*)x_b, MF * D / 4);
  cvt_w_t<<<dim3(32, 32), 256, 0, stream>>>(Wq, WqT);
  cvt_w_t<<<dim3(32, 32), 256, 0, stream>>>(Wk, WkT);
  cvt_w_t<<<dim3(32, 32), 256, 0, stream>>>(Wv, WvT);
  cvt_w_t<<<dim3(32, 32), 256, 0, stream>>>(Wo, WoT);

  // 2. q = x Wq + bq, k = x Wk + bk   [8192 x 1024]
  gemm_nt<true, 1, 0><<<dim3(MF / 128, D / 128, 1), 256, 0, stream>>>(
      x_b, WqT, q_b, bq, MF, D, D, 0, 0, 0);
  gemm_nt<true, 1, 0><<<dim3(MF / 128, D / 128, 1), 256, 0, stream>>>(
      x_b, WkT, k_b, bk, MF, D, D, 0, 0, 0);
  // 3. vT[b] = Wv^T x[b]^T + bv  -> [D][S] per batch (bias over rows)
  gemm_nt<true, 2, 0><<<dim3(D / 128, S / 128, Bb), 256, 0, stream>>>(
      WvT, x_b, vT_b, bv, D, S, D, 0, (long)S * D, (long)D * S);

  // 4. scores[b] = q[b] k[b]^T  (fp32, causal block skip)
  gemm_nt<false, 0, 1><<<dim3(S / 128, S / 128, Bb), 256, 0, stream>>>(
      q_b, k_b, sc, nullptr, S, S, D, (long)S * D, (long)S * D, (long)S * S);

  // 5. causal softmax rows -> bf16 probs
  softmax_causal<<<dim3(Bb * S), 256, 0, stream>>>(sc, probs);

  // 6. attn[b] = probs[b] v[b]  (k-limit causal)
  gemm_nt<true, 0, 2><<<dim3(S / 128, D / 128, Bb), 256, 0, stream>>>(
      probs, vT_b, attn, nullptr, S, D, S, (long)S * S, (long)D * S, (long)S * D);

  // 7. out = attn Wo + bo (fp32)
  gemm_nt<false, 1, 0><<<dim3(MF / 128, D / 128, 1), 256, 0, stream>>>(
      attn, WoT, out, bo, MF, D, D, 0, 0, 0);
}

// Round 2
// 285.321 us; speedup vs baseline: 1.2157x; 1.2157x over previous
//
#include <hip/hip_runtime.h>
#include <stdint.h>

typedef __bf16 bf16_t;
typedef __bf16 bf16x8 __attribute__((ext_vector_type(8)));
typedef __bf16 bf16x4 __attribute__((ext_vector_type(4)));
typedef float  f32x4  __attribute__((ext_vector_type(4)));

#define DEV __device__ __forceinline__

constexpr int S = 2048, D = 1024, BATCH = 4, MF = BATCH * S;

// async global->LDS, 16B per lane. LDS dest is wave-uniform base + lane*16.
DEV void gload16(const void* g, void* l) {
  __builtin_amdgcn_global_load_lds(
      (const __attribute__((address_space(1))) void*)g,
      (__attribute__((address_space(3))) void*)(uint32_t)(uintptr_t)l,
      16, 0, 0);
}

// ---------------------------------------------------------------------------
// NT GEMM core: C[m][n] = sum_k A[m][k]*B[n][k], bf16 in, fp32 acc.
// Tile 128x128, BK=64, 256 thr (4 waves, 2x2 of 64x64). LDS rows are 64 bf16
// (128 B = 32 banks); 16-B chunks XOR-swizzled by (row&7) to kill the 16-way
// bank conflict on ds_read_b128 (swizzle applied on the GLOBAL source side so
// global_load_lds's lane-contiguous LDS dest is preserved).
// EP: 0 = fp32 out + bias[n] (out-proj)
//     1 = QKV split: q/k bf16 [MF][D], v transposed -> vT[b][D][S], bias[n]
//     2 = scores: exp(acc/32) (causal mask), bf16 probs + partial row sums;
//         tile-skip tn>tm
//     3 = PV: bf16 out scaled by inv_l[row]; k-limit kmax=m0+128
// ---------------------------------------------------------------------------
template<int EP>
__global__ __launch_bounds__(256, 2) void gemm_core(
    const bf16_t* __restrict__ A, const bf16_t* __restrict__ B,
    void* __restrict__ C0, void* __restrict__ C1, void* __restrict__ C2,
    const float* __restrict__ aux, float* __restrict__ part,
    int M, int N, int K, long sA, long sB)
{
  const int tm = blockIdx.x, tn = blockIdx.y, bz = blockIdx.z;
  if (EP == 2 && tn > tm) return;             // fully-masked score tile
  const int m0 = tm * 128, n0 = tn * 128;
  int kmax = K;
  if (EP == 3) { int t = m0 + 128; kmax = t < K ? t : K; }
  A += (long)bz * sA;
  B += (long)bz * sB;

  __shared__ __align__(16) bf16_t ldsA[128 * 64];
  __shared__ __align__(16) bf16_t ldsB[128 * 64];

  const int tid  = threadIdx.x;
  const int lane = tid & 63;
  const int wave = tid >> 6;
  const int wm = wave & 1, wn = wave >> 1;
  const int l8r = lane >> 3;                  // row within 8-row staging block
  const int swz = ((lane & 7) ^ (lane >> 3)) * 8;  // swizzled k-chunk (elems)
  const int cl  = lane & 15;                  // fragment m/n index
  const int qd  = lane >> 4;                  // quad -> k-slice
  const int ch0 = ((qd ^ (cl & 7)) * 8);      // swizzled read chunk, kk=0

  f32x4 acc[4][4] = {};

  for (int k0 = 0; k0 < kmax; k0 += 64) {
    #pragma unroll
    for (int t = 0; t < 4; ++t) {
      const int rb = wave * 4 + t;
      gload16(A + (long)(m0 + rb * 8 + l8r) * K + (k0 + swz), &ldsA[rb * 512]);
      gload16(B + (long)(n0 + rb * 8 + l8r) * K + (k0 + swz), &ldsB[rb * 512]);
    }
    __syncthreads();
    #pragma unroll
    for (int kk = 0; kk < 64; kk += 32) {
      bf16x8 af[4], bg[4];
      #pragma unroll
      for (int i = 0; i < 4; ++i)
        af[i] = *(const bf16x8*)&ldsA[(wm * 64 + i * 16 + cl) * 64 + (ch0 ^ kk)];
      #pragma unroll
      for (int j = 0; j < 4; ++j)
        bg[j] = *(const bf16x8*)&ldsB[(wn * 64 + j * 16 + cl) * 64 + (ch0 ^ kk)];
      #pragma unroll
      for (int i = 0; i < 4; ++i)
        #pragma unroll
        for (int j = 0; j < 4; ++j)
          acc[i][j] = __builtin_amdgcn_mfma_f32_16x16x32_bf16(af[i], bg[j], acc[i][j], 0, 0, 0);
    }
    __syncthreads();
  }

  // Epilogues. C/D layout: col = lane&15, row = (lane>>4)*4 + reg.
  #pragma unroll
  for (int i = 0; i < 4; ++i) {
    const int gm0 = m0 + wm * 64 + i * 16 + qd * 4;

    if (EP == 0) {                            // out-proj: fp32 + bias[n]
      float* Co = (float*)C0;
      #pragma unroll
      for (int j = 0; j < 4; ++j) {
        const int gn = n0 + wn * 64 + j * 16 + cl;
        const float bn = aux[gn];
        #pragma unroll
        for (int r = 0; r < 4; ++r)
          Co[(long)(gm0 + r) * D + gn] = acc[i][j][r] + bn;
      }
    }

    if (EP == 1) {                            // fused QKV split store
      bf16_t* q  = (bf16_t*)C0;
      bf16_t* k  = (bf16_t*)C1;
      bf16_t* vT = (bf16_t*)C2;
      #pragma unroll
      for (int j = 0; j < 4; ++j) {
        const int gn  = n0 + wn * 64 + j * 16 + cl;
        const int sec = gn >> 10, ln = gn & 1023;
        const float bn = aux[gn];
        if (sec == 2) {                       // v: store transposed, 4x bf16
          const int z = gm0 >> 11, s0 = gm0 & 2047;
          bf16x4 v4;
          #pragma unroll
          for (int r = 0; r < 4; ++r) v4[r] = (bf16_t)(acc[i][j][r] + bn);
          *(bf16x4*)&vT[((long)z * D + ln) * S + s0] = v4;
        } else {
          bf16_t* dst = (sec == 0) ? q : k;
          #pragma unroll
          for (int r = 0; r < 4; ++r)
            dst[(long)(gm0 + r) * D + ln] = (bf16_t)(acc[i][j][r] + bn);
        }
      }
    }

    if (EP == 2) {                            // scores -> exp probs + partials
      bf16_t* probs = (bf16_t*)C0 + (long)bz * S * S;
      float ls[4] = {0.f, 0.f, 0.f, 0.f};
      #pragma unroll
      for (int j = 0; j < 4; ++j) {
        const int gn = n0 + wn * 64 + j * 16 + cl;
        #pragma unroll
        for (int r = 0; r < 4; ++r) {
          const int gm = gm0 + r;
          const float e = (gn <= gm) ? __expf(acc[i][j][r] * 0.03125f) : 0.0f;
          probs[(long)gm * S + gn] = (bf16_t)e;
          ls[r] += e;
        }
      }
      #pragma unroll
      for (int r = 0; r < 4; ++r) {
        float v = ls[r];
        v += __shfl_xor(v, 1); v += __shfl_xor(v, 2);
        v += __shfl_xor(v, 4); v += __shfl_xor(v, 8);
        if (cl == 0)
          part[((long)bz * S + (gm0 + r)) * 32 + tn * 2 + wn] = v;
      }
    }

    if (EP == 3) {                            // PV: scale by inv_l, bf16 out
      bf16_t* attn = (bf16_t*)C0 + (long)bz * S * D;
      const float* invl = aux + (long)bz * S;
      float scl[4];
      #pragma unroll
      for (int r = 0; r < 4; ++r) scl[r] = invl[gm0 + r];
      #pragma unroll
      for (int j = 0; j < 4; ++j) {
        const int gn = n0 + wn * 64 + j * 16 + cl;
        #pragma unroll
        for (int r = 0; r < 4; ++r)
          attn[(long)(gm0 + r) * D + gn] = (bf16_t)(acc[i][j][r] * scl[r]);
      }
    }
  }
}

// inv_l[row] = 1 / sum(valid partials). Row tile tm has (tm+1)*2 valid entries.
__global__ __launch_bounds__(256) void reduce_invl(
    const float* __restrict__ part, float* __restrict__ invl)
{
  const int r = blockIdx.x * 256 + threadIdx.x;   // 0..MF-1
  const int row = r & (S - 1);
  const int cnt = ((row >> 7) + 1) * 2;
  const float* p = part + (long)r * 32;
  float s = 0.f;
  for (int j = 0; j < cnt; ++j) s += p[j];
  invl[r] = 1.0f / s;
}

// fp32 -> bf16 elementwise (x), 4 elems/thread
__global__ __launch_bounds__(256) void cvt_x(
    const float4* __restrict__ in, bf16x4* __restrict__ out, int n4)
{
  const int i = blockIdx.x * 256 + threadIdx.x;
  if (i >= n4) return;
  float4 f = in[i];
  bf16x4 o;
  o.x = (__bf16)f.x; o.y = (__bf16)f.y; o.z = (__bf16)f.z; o.w = (__bf16)f.w;
  out[i] = o;
}

// W[k][n] fp32 (1024x1024) -> WT[n][k] bf16, 32x32 LDS tile transpose
__global__ __launch_bounds__(256) void cvt_w_t(
    const float* __restrict__ W, bf16_t* __restrict__ WT)
{
  __shared__ float t[32][33];
  const int bx = blockIdx.x, by = blockIdx.y;
  const int tx = threadIdx.x & 31, ty = threadIdx.x >> 5;  // 32 x 8
  #pragma unroll
  for (int dy = 0; dy < 32; dy += 8)
    t[ty + dy][tx] = W[(long)(by * 32 + ty + dy) * 1024 + bx * 32 + tx];
  __syncthreads();
  #pragma unroll
  for (int dy = 0; dy < 32; dy += 8)
    WT[(long)(bx * 32 + ty + dy) * 1024 + by * 32 + tx] = (bf16_t)t[tx][ty + dy];
}

// ---------------------------------------------------------------------------
extern "C" void kernel_launch(void* const* d_in, const int* in_sizes, int n_in,
                              void* d_out, int out_size, void* d_ws, size_t ws_size,
                              hipStream_t stream) {
  const float* x  = (const float*)d_in[0];
  const float* Wq = (const float*)d_in[1];
  const float* bq = (const float*)d_in[2];
  const float* Wk = (const float*)d_in[3];
  const float* bk = (const float*)d_in[4];
  const float* Wv = (const float*)d_in[5];
  const float* bv = (const float*)d_in[6];
  const float* Wo = (const float*)d_in[7];
  const float* bo = (const float*)d_in[8];
  float* out = (float*)d_out;

  size_t off = 0;
  auto alloc = [&](size_t bytes) -> void* {
    void* p = (char*)d_ws + off;
    off += (bytes + 255) & ~(size_t)255;
    return p;
  };
  bf16_t* x_b   = (bf16_t*)alloc((size_t)MF * D * 2);          // 16.8 MB
  bf16_t* WqkvT = (bf16_t*)alloc((size_t)3 * D * D * 2);       // stacked [3D][D]
  bf16_t* WoT   = (bf16_t*)alloc((size_t)D * D * 2);
  float*  bqkv  = (float*) alloc((size_t)3 * D * 4);           // stacked bias
  bf16_t* q_b   = (bf16_t*)alloc((size_t)MF * D * 2);
  bf16_t* k_b   = (bf16_t*)alloc((size_t)MF * D * 2);
  bf16_t* vT_b  = (bf16_t*)alloc((size_t)BATCH * D * S * 2);   // [b][D][S]
  bf16_t* probs = (bf16_t*)alloc((size_t)BATCH * S * S * 2);   // 33.5 MB
  float*  part  = (float*) alloc((size_t)MF * 32 * 4);         // 1 MB
  float*  invl  = (float*) alloc((size_t)MF * 4);
  bf16_t* attn  = (bf16_t*)alloc((size_t)MF * D * 2);

  // 0. stacked qkv bias (d2d async copies are graph-capture safe)
  hipMemcpyAsync(bqkv,            bq, D * 4, hipMemcpyDeviceToDevice, stream);
  hipMemcpyAsync(bqkv + D,        bk, D * 4, hipMemcpyDeviceToDevice, stream);
  hipMemcpyAsync(bqkv + 2 * D,    bv, D * 4, hipMemcpyDeviceToDevice, stream);

  // 1. converts: x -> bf16; weights -> bf16 transposed ([n][k]) so every GEMM
  //    is NT with contiguous 16-B fragment runs.
  cvt_x<<<dim3((MF * D / 4 + 255) / 256), 256, 0, stream>>>(
      (const float4*)x, (bf16x4*)x_b, MF * D / 4);
  cvt_w_t<<<dim3(32, 32), 256, 0, stream>>>(Wq, WqkvT);
  cvt_w_t<<<dim3(32, 32), 256, 0, stream>>>(Wk, WqkvT + (size_t)D * D);
  cvt_w_t<<<dim3(32, 32), 256, 0, stream>>>(Wv, WqkvT + (size_t)2 * D * D);
  cvt_w_t<<<dim3(32, 32), 256, 0, stream>>>(Wo, WoT);

  // 2. fused QKV projection: [8192 x 3072 x 1024]; v lands transposed
  gemm_core<1><<<dim3(MF / 128, 3 * D / 128, 1), 256, 0, stream>>>(
      x_b, WqkvT, q_b, k_b, vT_b, bqkv, nullptr, MF, 3 * D, D, 0, 0);

  // 3. scores = q k^T per batch -> exp(./32) bf16 probs + partial row sums
  gemm_core<2><<<dim3(S / 128, S / 128, BATCH), 256, 0, stream>>>(
      q_b, k_b, probs, nullptr, nullptr, nullptr, part,
      S, S, D, (long)S * D, (long)S * D);

  // 4. inv row sums
  reduce_invl<<<dim3(MF / 256), 256, 0, stream>>>(part, invl);

  // 5. attn = (probs v) * inv_l  (k-limit causal)
  gemm_core<3><<<dim3(S / 128, D / 128, BATCH), 256, 0, stream>>>(
      probs, vT_b, attn, nullptr, nullptr, invl, nullptr,
      S, D, S, (long)S * S, (long)D * S);

  // 6. out = attn Wo + bo (fp32)
  gemm_core<0><<<dim3(MF / 128, D / 128, 1), 256, 0, stream>>>(
      attn, WoT, out, nullptr, nullptr, bo, nullptr, MF, D, D, 0, 0);
}

// Round 3
// 280.150 us; speedup vs baseline: 1.2382x; 1.0185x over previous
//
#include <hip/hip_runtime.h>
#include <stdint.h>

typedef __bf16 bf16_t;
typedef __bf16 bf16x8 __attribute__((ext_vector_type(8)));
typedef __bf16 bf16x4 __attribute__((ext_vector_type(4)));
typedef float  f32x4  __attribute__((ext_vector_type(4)));

#define DEV __device__ __forceinline__

constexpr int S = 2048, D = 1024, BATCH = 4, MF = BATCH * S;

// async global->LDS, 16B per lane. LDS dest is wave-uniform base + lane*16.
DEV void gload16(const void* g, void* l) {
  __builtin_amdgcn_global_load_lds(
      (const __attribute__((address_space(1))) void*)g,
      (__attribute__((address_space(3))) void*)(uint32_t)(uintptr_t)l,
      16, 0, 0);
}

// ---------------------------------------------------------------------------
// NT GEMM core: C[m][n] = sum_k A[m][k]*B[n][k], bf16 in, fp32 acc.
// Tile 128x128, BK=64, 256 thr (4 waves, 2x2 of 64x64). LDS rows are 64 bf16
// (128 B = 32 banks); 16-B chunks XOR-swizzled by (row&7) to kill the 16-way
// bank conflict on ds_read_b128 (swizzle applied on the GLOBAL source side so
// global_load_lds's lane-contiguous LDS dest is preserved).
// __launch_bounds__(256,4): 4 waves/EU -> 4 blocks/CU co-resident (reg budget
// 128 incl. AGPR acc), so other blocks fill each block's barrier-drain stall.
// EP: 0 = fp32 out + bias[n] (out-proj)
//     1 = QKV split: q/k bf16 [MF][D], v transposed -> vT[b][D][S], bias[n]
//     2 = scores: exp(acc/32) (causal), bf16 probs + partial row sums;
//         triangular-packed grid (blockIdx.x in [0,136))
//     3 = PV: bf16 out scaled by inv_l[row]; k-limit kmax=m0+128; dispatch
//         order reversed so long-K blocks start first
// ---------------------------------------------------------------------------
template<int EP>
__global__ __launch_bounds__(256, 4) void gemm_core(
    const bf16_t* __restrict__ A, const bf16_t* __restrict__ B,
    void* __restrict__ C0, void* __restrict__ C1, void* __restrict__ C2,
    const float* __restrict__ aux, float* __restrict__ part,
    int M, int N, int K, long sA, long sB)
{
  int tm = blockIdx.x, tn = blockIdx.y;
  const int bz = blockIdx.z;
  if (EP == 2) {                              // triangular decode: tn <= tm
    const int t = blockIdx.x;
    tm = (int)((sqrtf(8.0f * t + 1.0f) - 1.0f) * 0.5f);
    while ((tm + 1) * (tm + 2) / 2 <= t) ++tm;
    while (tm * (tm + 1) / 2 > t) --tm;
    tn = t - tm * (tm + 1) / 2;
  }
  if (EP == 3) tm = (int)gridDim.x - 1 - blockIdx.x;  // long blocks first
  const int m0 = tm * 128, n0 = tn * 128;
  int kmax = K;
  if (EP == 3) { int t = m0 + 128; kmax = t < K ? t : K; }
  A += (long)bz * sA;
  B += (long)bz * sB;

  __shared__ __align__(16) bf16_t ldsA[128 * 64];
  __shared__ __align__(16) bf16_t ldsB[128 * 64];

  const int tid  = threadIdx.x;
  const int lane = tid & 63;
  const int wave = tid >> 6;
  const int wm = wave & 1, wn = wave >> 1;
  const int l8r = lane >> 3;                  // row within 8-row staging block
  const int swz = ((lane & 7) ^ (lane >> 3)) * 8;  // swizzled k-chunk (elems)
  const int cl  = lane & 15;                  // fragment m/n index
  const int qd  = lane >> 4;                  // quad -> k-slice
  const int ch0 = ((qd ^ (cl & 7)) * 8);      // swizzled read chunk, kk=0

  f32x4 acc[4][4] = {};

  for (int k0 = 0; k0 < kmax; k0 += 64) {
    #pragma unroll
    for (int t = 0; t < 4; ++t) {
      const int rb = wave * 4 + t;
      gload16(A + (long)(m0 + rb * 8 + l8r) * K + (k0 + swz), &ldsA[rb * 512]);
      gload16(B + (long)(n0 + rb * 8 + l8r) * K + (k0 + swz), &ldsB[rb * 512]);
    }
    __syncthreads();
    #pragma unroll
    for (int kk = 0; kk < 64; kk += 32) {
      bf16x8 af[4], bg[4];
      #pragma unroll
      for (int i = 0; i < 4; ++i)
        af[i] = *(const bf16x8*)&ldsA[(wm * 64 + i * 16 + cl) * 64 + (ch0 ^ kk)];
      #pragma unroll
      for (int j = 0; j < 4; ++j)
        bg[j] = *(const bf16x8*)&ldsB[(wn * 64 + j * 16 + cl) * 64 + (ch0 ^ kk)];
      #pragma unroll
      for (int i = 0; i < 4; ++i)
        #pragma unroll
        for (int j = 0; j < 4; ++j)
          acc[i][j] = __builtin_amdgcn_mfma_f32_16x16x32_bf16(af[i], bg[j], acc[i][j], 0, 0, 0);
    }
    __syncthreads();
  }

  // Epilogues. C/D layout: col = lane&15, row = (lane>>4)*4 + reg.
  #pragma unroll
  for (int i = 0; i < 4; ++i) {
    const int gm0 = m0 + wm * 64 + i * 16 + qd * 4;

    if (EP == 0) {                            // out-proj: fp32 + bias[n]
      float* Co = (float*)C0;
      #pragma unroll
      for (int j = 0; j < 4; ++j) {
        const int gn = n0 + wn * 64 + j * 16 + cl;
        const float bn = aux[gn];
        #pragma unroll
        for (int r = 0; r < 4; ++r)
          Co[(long)(gm0 + r) * D + gn] = acc[i][j][r] + bn;
      }
    }

    if (EP == 1) {                            // fused QKV split store
      bf16_t* q  = (bf16_t*)C0;
      bf16_t* k  = (bf16_t*)C1;
      bf16_t* vT = (bf16_t*)C2;
      #pragma unroll
      for (int j = 0; j < 4; ++j) {
        const int gn  = n0 + wn * 64 + j * 16 + cl;
        const int sec = gn >> 10, ln = gn & 1023;
        const float bn = aux[gn];
        if (sec == 2) {                       // v: store transposed, 4x bf16
          const int z = gm0 >> 11, s0 = gm0 & 2047;
          bf16x4 v4;
          #pragma unroll
          for (int r = 0; r < 4; ++r) v4[r] = (bf16_t)(acc[i][j][r] + bn);
          *(bf16x4*)&vT[((long)z * D + ln) * S + s0] = v4;
        } else {
          bf16_t* dst = (sec == 0) ? q : k;
          #pragma unroll
          for (int r = 0; r < 4; ++r)
            dst[(long)(gm0 + r) * D + ln] = (bf16_t)(acc[i][j][r] + bn);
        }
      }
    }

    if (EP == 2) {                            // scores -> exp probs + partials
      bf16_t* probs = (bf16_t*)C0 + (long)bz * S * S;
      float ls[4] = {0.f, 0.f, 0.f, 0.f};
      #pragma unroll
      for (int j = 0; j < 4; ++j) {
        const int gn = n0 + wn * 64 + j * 16 + cl;
        #pragma unroll
        for (int r = 0; r < 4; ++r) {
          const int gm = gm0 + r;
          const float e = (gn <= gm) ? __expf(acc[i][j][r] * 0.03125f) : 0.0f;
          probs[(long)gm * S + gn] = (bf16_t)e;
          ls[r] += e;
        }
      }
      #pragma unroll
      for (int r = 0; r < 4; ++r) {
        float v = ls[r];
        v += __shfl_xor(v, 1); v += __shfl_xor(v, 2);
        v += __shfl_xor(v, 4); v += __shfl_xor(v, 8);
        if (cl == 0)
          part[((long)bz * S + (gm0 + r)) * 32 + tn * 2 + wn] = v;
      }
    }

    if (EP == 3) {                            // PV: scale by inv_l, bf16 out
      bf16_t* attn = (bf16_t*)C0 + (long)bz * S * D;
      const float* invl = aux + (long)bz * S;
      float scl[4];
      #pragma unroll
      for (int r = 0; r < 4; ++r) scl[r] = invl[gm0 + r];
      #pragma unroll
      for (int j = 0; j < 4; ++j) {
        const int gn = n0 + wn * 64 + j * 16 + cl;
        #pragma unroll
        for (int r = 0; r < 4; ++r)
          attn[(long)(gm0 + r) * D + gn] = (bf16_t)(acc[i][j][r] * scl[r]);
      }
    }
  }
}

// inv_l[row] = 1 / sum(valid partials). Row tile tm has (tm+1)*2 valid entries.
__global__ __launch_bounds__(256) void reduce_invl(
    const float* __restrict__ part, float* __restrict__ invl)
{
  const int r = blockIdx.x * 256 + threadIdx.x;   // 0..MF-1
  const int row = r & (S - 1);
  const int cnt = ((row >> 7) + 1) * 2;
  const float* p = part + (long)r * 32;
  float s = 0.f;
  for (int j = 0; j < cnt; ++j) s += p[j];
  invl[r] = 1.0f / s;
}

// fp32 -> bf16 elementwise (x), 4 elems/thread
__global__ __launch_bounds__(256) void cvt_x(
    const float4* __restrict__ in, bf16x4* __restrict__ out, int n4)
{
  const int i = blockIdx.x * 256 + threadIdx.x;
  if (i >= n4) return;
  float4 f = in[i];
  bf16x4 o;
  o.x = (__bf16)f.x; o.y = (__bf16)f.y; o.z = (__bf16)f.z; o.w = (__bf16)f.w;
  out[i] = o;
}

// 4x W[k][n] fp32 (1024x1024) -> WT[n][k] bf16 stacked, 32x32 LDS transpose.
// z selects {Wq,Wk,Wv,Wo}.
__global__ __launch_bounds__(256) void cvt_w_t4(
    const float* __restrict__ W0, const float* __restrict__ W1,
    const float* __restrict__ W2, const float* __restrict__ W3,
    bf16_t* __restrict__ dst)
{
  const float* W = (blockIdx.z == 0) ? W0 : (blockIdx.z == 1) ? W1
                 : (blockIdx.z == 2) ? W2 : W3;
  bf16_t* WT = dst + (size_t)blockIdx.z * D * D;
  __shared__ float t[32][33];
  const int bx = blockIdx.x, by = blockIdx.y;
  const int tx = threadIdx.x & 31, ty = threadIdx.x >> 5;  // 32 x 8
  #pragma unroll
  for (int dy = 0; dy < 32; dy += 8)
    t[ty + dy][tx] = W[(long)(by * 32 + ty + dy) * 1024 + bx * 32 + tx];
  __syncthreads();
  #pragma unroll
  for (int dy = 0; dy < 32; dy += 8)
    WT[(long)(bx * 32 + ty + dy) * 1024 + by * 32 + tx] = (bf16_t)t[tx][ty + dy];
}

// stacked qkv bias: bqkv[0:1024)=bq, [1024:2048)=bk, [2048:3072)=bv
__global__ __launch_bounds__(256) void stack_bias(
    const float* __restrict__ bq, const float* __restrict__ bk,
    const float* __restrict__ bv, float* __restrict__ o)
{
  const int i = blockIdx.x * 256 + threadIdx.x;     // 0..3071
  const float* s = (i < 1024) ? bq : (i < 2048) ? bk : bv;
  o[i] = s[i & 1023];
}

// ---------------------------------------------------------------------------
extern "C" void kernel_launch(void* const* d_in, const int* in_sizes, int n_in,
                              void* d_out, int out_size, void* d_ws, size_t ws_size,
                              hipStream_t stream) {
  const float* x  = (const float*)d_in[0];
  const float* Wq = (const float*)d_in[1];
  const float* bq = (const float*)d_in[2];
  const float* Wk = (const float*)d_in[3];
  const float* bk = (const float*)d_in[4];
  const float* Wv = (const float*)d_in[5];
  const float* bv = (const float*)d_in[6];
  const float* Wo = (const float*)d_in[7];
  const float* bo = (const float*)d_in[8];
  float* out = (float*)d_out;

  size_t off = 0;
  auto alloc = [&](size_t bytes) -> void* {
    void* p = (char*)d_ws + off;
    off += (bytes + 255) & ~(size_t)255;
    return p;
  };
  bf16_t* x_b   = (bf16_t*)alloc((size_t)MF * D * 2);          // 16.8 MB
  bf16_t* Wall  = (bf16_t*)alloc((size_t)4 * D * D * 2);       // [Wq|Wk|Wv|Wo]^T
  float*  bqkv  = (float*) alloc((size_t)3 * D * 4);           // stacked bias
  bf16_t* q_b   = (bf16_t*)alloc((size_t)MF * D * 2);
  bf16_t* k_b   = (bf16_t*)alloc((size_t)MF * D * 2);
  bf16_t* vT_b  = (bf16_t*)alloc((size_t)BATCH * D * S * 2);   // [b][D][S]
  bf16_t* probs = (bf16_t*)alloc((size_t)BATCH * S * S * 2);   // 33.5 MB
  float*  part  = (float*) alloc((size_t)MF * 32 * 4);         // 1 MB
  float*  invl  = (float*) alloc((size_t)MF * 4);
  bf16_t* attn  = (bf16_t*)alloc((size_t)MF * D * 2);
  bf16_t* WqkvT = Wall;                       // [3D][D]
  bf16_t* WoT   = Wall + (size_t)3 * D * D;

  // 1. preamble: x -> bf16; weights -> bf16 transposed ([n][k]); bias stack
  cvt_x<<<dim3((MF * D / 4 + 255) / 256), 256, 0, stream>>>(
      (const float4*)x, (bf16x4*)x_b, MF * D / 4);
  cvt_w_t4<<<dim3(32, 32, 4), 256, 0, stream>>>(Wq, Wk, Wv, Wo, Wall);
  stack_bias<<<dim3(12), 256, 0, stream>>>(bq, bk, bv, bqkv);

  // 2. fused QKV projection: [8192 x 3072 x 1024]; v lands transposed
  gemm_core<1><<<dim3(MF / 128, 3 * D / 128, 1), 256, 0, stream>>>(
      x_b, WqkvT, q_b, k_b, vT_b, bqkv, nullptr, MF, 3 * D, D, 0, 0);

  // 3. scores = q k^T per batch -> exp(./32) bf16 probs + partial row sums
  //    (triangular-packed grid: 136 tiles per batch)
  gemm_core<2><<<dim3(136, 1, BATCH), 256, 0, stream>>>(
      q_b, k_b, probs, nullptr, nullptr, nullptr, part,
      S, S, D, (long)S * D, (long)S * D);

  // 4. inv row sums
  reduce_invl<<<dim3(MF / 256), 256, 0, stream>>>(part, invl);

  // 5. attn = (probs v) * inv_l  (k-limit causal, long blocks first)
  gemm_core<3><<<dim3(S / 128, D / 128, BATCH), 256, 0, stream>>>(
      probs, vT_b, attn, nullptr, nullptr, invl, nullptr,
      S, D, S, (long)S * S, (long)D * S);

  // 6. out = attn Wo + bo (fp32)
  gemm_core<0><<<dim3(MF / 128, D / 128, 1), 256, 0, stream>>>(
      attn, WoT, out, nullptr, nullptr, bo, nullptr, MF, D, D, 0, 0);
}

// Round 4
// 251.699 us; speedup vs baseline: 1.3781x; 1.1130x over previous
//
#include <hip/hip_runtime.h>
#include <stdint.h>

typedef __bf16 bf16_t;
typedef __bf16 bf16x8 __attribute__((ext_vector_type(8)));
typedef __bf16 bf16x4 __attribute__((ext_vector_type(4)));
typedef float  f32x4  __attribute__((ext_vector_type(4)));

#define DEV __device__ __forceinline__

constexpr int S = 2048, D = 1024, BATCH = 4, MF = BATCH * S;

// async global->LDS, 16B per lane. LDS dest is wave-uniform base + lane*16.
DEV void gload16(const void* g, void* l) {
  __builtin_amdgcn_global_load_lds(
      (const __attribute__((address_space(1))) void*)g,
      (__attribute__((address_space(3))) void*)(uint32_t)(uintptr_t)l,
      16, 0, 0);
}

// ---------------------------------------------------------------------------
// Shared NT GEMM body: C[m][n] = sum_k A[m][k]*B[n][k], bf16 in, fp32 acc.
// Tile 128x128, BK=64, 256 thr (4 waves, 2x2 of 64x64). 16-B chunks
// XOR-swizzled by (row&7) on the GLOBAL source side (keeps global_load_lds's
// lane-contiguous LDS dest) -> 0 bank conflicts on ds_read_b128 (verified R2).
// EP: 0 oproj fp32+bias[n]; 1 QKV split (v transposed); 2 scores->exp probs
//     + partial sums; 3 PV scaled by inv_l.
// ---------------------------------------------------------------------------
template<int EP>
DEV void gemm_body(int tm, int tn, int bz,
                   const bf16_t* __restrict__ A, const bf16_t* __restrict__ B,
                   void* __restrict__ C0, void* __restrict__ C1,
                   void* __restrict__ C2, const float* __restrict__ aux,
                   float* __restrict__ part, int K, int kmax,
                   bf16_t* ldsA, bf16_t* ldsB)
{
  const int m0 = tm * 128, n0 = tn * 128;
  const int tid  = threadIdx.x;
  const int lane = tid & 63;
  const int wave = tid >> 6;
  const int wm = wave & 1, wn = wave >> 1;
  const int l8r = lane >> 3;                  // row within 8-row staging block
  const int swz = ((lane & 7) ^ (lane >> 3)) * 8;  // swizzled k-chunk (elems)
  const int cl  = lane & 15;                  // fragment m/n index
  const int qd  = lane >> 4;                  // quad -> k-slice
  const int ch0 = ((qd ^ (cl & 7)) * 8);      // swizzled read chunk, kk=0

  f32x4 acc[4][4] = {};

  for (int k0 = 0; k0 < kmax; k0 += 64) {
    #pragma unroll
    for (int t = 0; t < 4; ++t) {
      const int rb = wave * 4 + t;
      gload16(A + (long)(m0 + rb * 8 + l8r) * K + (k0 + swz), &ldsA[rb * 512]);
      gload16(B + (long)(n0 + rb * 8 + l8r) * K + (k0 + swz), &ldsB[rb * 512]);
    }
    __syncthreads();
    #pragma unroll
    for (int kk = 0; kk < 64; kk += 32) {
      bf16x8 af[4], bg[4];
      #pragma unroll
      for (int i = 0; i < 4; ++i)
        af[i] = *(const bf16x8*)&ldsA[(wm * 64 + i * 16 + cl) * 64 + (ch0 ^ kk)];
      #pragma unroll
      for (int j = 0; j < 4; ++j)
        bg[j] = *(const bf16x8*)&ldsB[(wn * 64 + j * 16 + cl) * 64 + (ch0 ^ kk)];
      #pragma unroll
      for (int i = 0; i < 4; ++i)
        #pragma unroll
        for (int j = 0; j < 4; ++j)
          acc[i][j] = __builtin_amdgcn_mfma_f32_16x16x32_bf16(af[i], bg[j], acc[i][j], 0, 0, 0);
    }
    __syncthreads();
  }

  // Epilogues. C/D layout: col = lane&15, row = (lane>>4)*4 + reg.
  #pragma unroll
  for (int i = 0; i < 4; ++i) {
    const int gm0 = m0 + wm * 64 + i * 16 + qd * 4;

    if (EP == 0) {                            // out-proj: fp32 + bias[n]
      float* Co = (float*)C0;
      #pragma unroll
      for (int j = 0; j < 4; ++j) {
        const int gn = n0 + wn * 64 + j * 16 + cl;
        const float bn = aux[gn];
        #pragma unroll
        for (int r = 0; r < 4; ++r)
          Co[(long)(gm0 + r) * D + gn] = acc[i][j][r] + bn;
      }
    }

    if (EP == 1) {                            // fused QKV split store
      bf16_t* q  = (bf16_t*)C0;
      bf16_t* k  = (bf16_t*)C1;
      bf16_t* vT = (bf16_t*)C2;
      #pragma unroll
      for (int j = 0; j < 4; ++j) {
        const int gn  = n0 + wn * 64 + j * 16 + cl;
        const int sec = gn >> 10, ln = gn & 1023;
        const float bn = aux[gn];
        if (sec == 2) {                       // v: store transposed, 4x bf16
          const int z = gm0 >> 11, s0 = gm0 & 2047;
          bf16x4 v4;
          #pragma unroll
          for (int r = 0; r < 4; ++r) v4[r] = (bf16_t)(acc[i][j][r] + bn);
          *(bf16x4*)&vT[((long)z * D + ln) * S + s0] = v4;
        } else {
          bf16_t* dst = (sec == 0) ? q : k;
          #pragma unroll
          for (int r = 0; r < 4; ++r)
            dst[(long)(gm0 + r) * D + ln] = (bf16_t)(acc[i][j][r] + bn);
        }
      }
    }

    if (EP == 2) {                            // scores -> exp probs + partials
      bf16_t* probs = (bf16_t*)C0 + (long)bz * S * S;
      float ls[4] = {0.f, 0.f, 0.f, 0.f};
      #pragma unroll
      for (int j = 0; j < 4; ++j) {
        const int gn = n0 + wn * 64 + j * 16 + cl;
        #pragma unroll
        for (int r = 0; r < 4; ++r) {
          const int gm = gm0 + r;
          const float e = (gn <= gm) ? __expf(acc[i][j][r] * 0.03125f) : 0.0f;
          probs[(long)gm * S + gn] = (bf16_t)e;
          ls[r] += e;
        }
      }
      #pragma unroll
      for (int r = 0; r < 4; ++r) {
        float v = ls[r];
        v += __shfl_xor(v, 1); v += __shfl_xor(v, 2);
        v += __shfl_xor(v, 4); v += __shfl_xor(v, 8);
        if (cl == 0)
          part[((long)bz * S + (gm0 + r)) * 32 + tn * 2 + wn] = v;
      }
    }

    if (EP == 3) {                            // PV: scale by inv_l, bf16 out
      bf16_t* attn = (bf16_t*)C0 + (long)bz * S * D;
      const float* invl = aux + (long)bz * S;
      float scl[4];
      #pragma unroll
      for (int r = 0; r < 4; ++r) scl[r] = invl[gm0 + r];
      #pragma unroll
      for (int j = 0; j < 4; ++j) {
        const int gn = n0 + wn * 64 + j * 16 + cl;
        #pragma unroll
        for (int r = 0; r < 4; ++r)
          attn[(long)(gm0 + r) * D + gn] = (bf16_t)(acc[i][j][r] * scl[r]);
      }
    }
  }
}

// QKV: persistent, 768 blocks x 2 tiles; both tiles share tm (A-panel reuse).
__global__ __launch_bounds__(256, 4) void gemm_qkv(
    const bf16_t* __restrict__ A, const bf16_t* __restrict__ B,
    bf16_t* q, bf16_t* k, bf16_t* vT, const float* __restrict__ bias)
{
  __shared__ __align__(16) bf16_t lA[128 * 64], lB[128 * 64];
  #pragma unroll
  for (int t = 0; t < 2; ++t) {
    const int l = (int)blockIdx.x + t * 768;       // 1536 tiles total
    gemm_body<1>(l & 63, l >> 6, 0, A, B, q, k, vT, bias, nullptr,
                 1024, 1024, lA, lB);
  }
}

// Scores: 544 blocks. blockIdx%8 = XCD (round-robin): 2 XCDs per batch, each
// takes a contiguous 68-tile half of the triangle -> per-XCD L2 working set
// ~5 MB instead of random scatter.
__global__ __launch_bounds__(256, 4) void gemm_sc(
    const bf16_t* __restrict__ q, const bf16_t* __restrict__ k,
    bf16_t* probs, float* part)
{
  __shared__ __align__(16) bf16_t lA[128 * 64], lB[128 * 64];
  const int l = blockIdx.x, xcd = l & 7, idx = l >> 3;
  const int bz = xcd >> 1;
  const int t  = (xcd & 1) * 68 + idx;             // triangular index 0..135
  int tm = (int)((sqrtf(8.0f * t + 1.0f) - 1.0f) * 0.5f);
  while ((tm + 1) * (tm + 2) / 2 <= t) ++tm;
  while (tm * (tm + 1) / 2 > t) --tm;
  const int tn = t - tm * (tm + 1) / 2;
  gemm_body<2>(tm, tn, bz, q + (long)bz * S * D, k + (long)bz * S * D,
               probs, nullptr, nullptr, nullptr, part, 1024, 1024, lA, lB);
}

// PV: 512 blocks. 2 XCDs per batch; m-pairs {m,15-m} interleaved so each XCD
// gets exactly 68 k-tiles of work (balanced) with all 8 n-tiles of one m
// adjacent (A-panel shared in L2).
__global__ __launch_bounds__(256, 4) void gemm_pv(
    const bf16_t* __restrict__ probs, const bf16_t* __restrict__ vT,
    bf16_t* attn, const float* __restrict__ invl)
{
  __shared__ __align__(16) bf16_t lA[128 * 64], lB[128 * 64];
  const int l = blockIdx.x, xcd = l & 7, idx = l >> 3;
  const int bz = xcd >> 1, half = xcd & 1;
  const int slot = idx >> 3, tn = idx & 7;
  const int tm = (slot & 1) ? (slot - 1 + half) : (15 - half - slot);
  const int kmax = (tm + 1) * 128;
  gemm_body<3>(tm, tn, bz, probs + (long)bz * S * S, vT + (long)bz * D * S,
               attn, nullptr, nullptr, invl, nullptr, 2048, kmax, lA, lB);
}

// Out-proj: plain 64x8 grid.
__global__ __launch_bounds__(256, 4) void gemm_oproj(
    const bf16_t* __restrict__ attn, const bf16_t* __restrict__ WoT,
    float* out, const float* __restrict__ bo)
{
  __shared__ __align__(16) bf16_t lA[128 * 64], lB[128 * 64];
  gemm_body<0>(blockIdx.x, blockIdx.y, 0, attn, WoT, out, nullptr, nullptr,
               bo, nullptr, 1024, 1024, lA, lB);
}

// inv_l[row] = 1 / sum(valid partials). Row tile tm has (tm+1)*2 valid entries.
__global__ __launch_bounds__(256) void reduce_invl(
    const float* __restrict__ part, float* __restrict__ invl)
{
  const int r = blockIdx.x * 256 + threadIdx.x;   // 0..MF-1
  const int row = r & (S - 1);
  const int cnt = ((row >> 7) + 1) * 2;
  const float* p = part + (long)r * 32;
  float s = 0.f;
  for (int j = 0; j < cnt; ++j) s += p[j];
  invl[r] = 1.0f / s;
}

// fp32 -> bf16 elementwise (x), 4 elems/thread
__global__ __launch_bounds__(256) void cvt_x(
    const float4* __restrict__ in, bf16x4* __restrict__ out, int n4)
{
  const int i = blockIdx.x * 256 + threadIdx.x;
  if (i >= n4) return;
  float4 f = in[i];
  bf16x4 o;
  o.x = (__bf16)f.x; o.y = (__bf16)f.y; o.z = (__bf16)f.z; o.w = (__bf16)f.w;
  out[i] = o;
}

// 4x W[k][n] fp32 (1024x1024) -> WT[n][k] bf16 stacked, 32x32 LDS transpose.
__global__ __launch_bounds__(256) void cvt_w_t4(
    const float* __restrict__ W0, const float* __restrict__ W1,
    const float* __restrict__ W2, const float* __restrict__ W3,
    bf16_t* __restrict__ dst)
{
  const float* W = (blockIdx.z == 0) ? W0 : (blockIdx.z == 1) ? W1
                 : (blockIdx.z == 2) ? W2 : W3;
  bf16_t* WT = dst + (size_t)blockIdx.z * D * D;
  __shared__ float t[32][33];
  const int bx = blockIdx.x, by = blockIdx.y;
  const int tx = threadIdx.x & 31, ty = threadIdx.x >> 5;  // 32 x 8
  #pragma unroll
  for (int dy = 0; dy < 32; dy += 8)
    t[ty + dy][tx] = W[(long)(by * 32 + ty + dy) * 1024 + bx * 32 + tx];
  __syncthreads();
  #pragma unroll
  for (int dy = 0; dy < 32; dy += 8)
    WT[(long)(bx * 32 + ty + dy) * 1024 + by * 32 + tx] = (bf16_t)t[tx][ty + dy];
}

// stacked qkv bias: bqkv[0:1024)=bq, [1024:2048)=bk, [2048:3072)=bv
__global__ __launch_bounds__(256) void stack_bias(
    const float* __restrict__ bq, const float* __restrict__ bk,
    const float* __restrict__ bv, float* __restrict__ o)
{
  const int i = blockIdx.x * 256 + threadIdx.x;     // 0..3071
  const float* s = (i < 1024) ? bq : (i < 2048) ? bk : bv;
  o[i] = s[i & 1023];
}

// ---------------------------------------------------------------------------
extern "C" void kernel_launch(void* const* d_in, const int* in_sizes, int n_in,
                              void* d_out, int out_size, void* d_ws, size_t ws_size,
                              hipStream_t stream) {
  const float* x  = (const float*)d_in[0];
  const float* Wq = (const float*)d_in[1];
  const float* bq = (const float*)d_in[2];
  const float* Wk = (const float*)d_in[3];
  const float* bk = (const float*)d_in[4];
  const float* Wv = (const float*)d_in[5];
  const float* bv = (const float*)d_in[6];
  const float* Wo = (const float*)d_in[7];
  const float* bo = (const float*)d_in[8];
  float* out = (float*)d_out;

  size_t off = 0;
  auto alloc = [&](size_t bytes) -> void* {
    void* p = (char*)d_ws + off;
    off += (bytes + 255) & ~(size_t)255;
    return p;
  };
  bf16_t* x_b   = (bf16_t*)alloc((size_t)MF * D * 2);          // 16.8 MB
  bf16_t* Wall  = (bf16_t*)alloc((size_t)4 * D * D * 2);       // [Wq|Wk|Wv|Wo]^T
  float*  bqkv  = (float*) alloc((size_t)3 * D * 4);           // stacked bias
  bf16_t* q_b   = (bf16_t*)alloc((size_t)MF * D * 2);
  bf16_t* k_b   = (bf16_t*)alloc((size_t)MF * D * 2);
  bf16_t* vT_b  = (bf16_t*)alloc((size_t)BATCH * D * S * 2);   // [b][D][S]
  bf16_t* probs = (bf16_t*)alloc((size_t)BATCH * S * S * 2);   // 33.5 MB
  float*  part  = (float*) alloc((size_t)MF * 32 * 4);         // 1 MB
  float*  invl  = (float*) alloc((size_t)MF * 4);
  bf16_t* attn  = (bf16_t*)alloc((size_t)MF * D * 2);
  bf16_t* WqkvT = Wall;                       // [3D][D]
  bf16_t* WoT   = Wall + (size_t)3 * D * D;

  // 1. preamble: x -> bf16; weights -> bf16 transposed ([n][k]); bias stack
  cvt_x<<<dim3((MF * D / 4 + 255) / 256), 256, 0, stream>>>(
      (const float4*)x, (bf16x4*)x_b, MF * D / 4);
  cvt_w_t4<<<dim3(32, 32, 4), 256, 0, stream>>>(Wq, Wk, Wv, Wo, Wall);
  stack_bias<<<dim3(12), 256, 0, stream>>>(bq, bk, bv, bqkv);

  // 2. fused QKV projection (persistent, 2 tiles/block sharing A-panel)
  gemm_qkv<<<dim3(768), 256, 0, stream>>>(x_b, WqkvT, q_b, k_b, vT_b, bqkv);

  // 3. scores = q k^T -> exp(./32) bf16 probs + partial row sums
  gemm_sc<<<dim3(544), 256, 0, stream>>>(q_b, k_b, probs, part);

  // 4. inv row sums
  reduce_invl<<<dim3(MF / 256), 256, 0, stream>>>(part, invl);

  // 5. attn = (probs v) * inv_l  (k-limit causal, XCD-balanced)
  gemm_pv<<<dim3(512), 256, 0, stream>>>(probs, vT_b, attn, invl);

  // 6. out = attn Wo + bo (fp32)
  gemm_oproj<<<dim3(64, 8), 256, 0, stream>>>(attn, WoT, out, bo);
}